// Round 1
// baseline (171.951 us; speedup 1.0000x reference)
//
#include <hip/hip_runtime.h>
#include <math.h>

#define D_DIM   1024
#define N_MODES 16
#define B_DIM   8
#define L_DIM   4096
#define CHUNK   64          // per-lane time chunk: 64 lanes * 64 = L
#define SCALE_F 0.25f       // sqrt(1/N)

__global__ __launch_bounds__(64)
void ema_scan_kernel(const float* __restrict__ x,
                     const float* __restrict__ p_logit,
                     const float* __restrict__ lqr,
                     const float* __restrict__ lqi,
                     const float* __restrict__ gr,
                     const float* __restrict__ gi,
                     const float* __restrict__ omega,
                     float* __restrict__ out)
{
    const int row  = blockIdx.x;              // b * D + d
    const int d    = row & (D_DIM - 1);
    const int lane = threadIdx.x & 63;

    // ---- per-mode pole q = exp(log_q) (wave-redundant setup, cheap) ----
    float qr[N_MODES], qi[N_MODES];
#pragma unroll
    for (int n = 0; n < N_MODES; ++n) {
        const int idx = d * N_MODES + n;
        const float er = __expf(lqr[idx]);
        float s, c;
        __sincosf(lqi[idx], &s, &c);
        qr[n] = er * c;
        qi[n] = er * s;
    }

    const float* xrow = x   + (size_t)row * L_DIM + (size_t)lane * CHUNK;
    float*       yrow = out + (size_t)row * L_DIM + (size_t)lane * CHUNK;

    float hr[N_MODES], hi[N_MODES];
#pragma unroll
    for (int n = 0; n < N_MODES; ++n) { hr[n] = 0.0f; hi[n] = 0.0f; }

    // ---- phase 1: local recurrence from zero state over this lane's chunk ----
#pragma unroll 2
    for (int j0 = 0; j0 < CHUNK; j0 += 4) {
        const float4 xv = *reinterpret_cast<const float4*>(xrow + j0);
        const float xs[4] = {xv.x, xv.y, xv.z, xv.w};
#pragma unroll
        for (int jj = 0; jj < 4; ++jj) {
            const float xe = xs[jj];
#pragma unroll
            for (int n = 0; n < N_MODES; ++n) {
                const float t  = fmaf(qr[n], hr[n], xe);
                const float nr = fmaf(-qi[n], hi[n], t);
                const float ni = fmaf(qr[n], hi[n], qi[n] * hr[n]);
                hr[n] = nr; hi[n] = ni;
            }
        }
    }

    // ---- ratio A = q^CHUNK via 6 squarings ----
    float rr[N_MODES], ri[N_MODES];
#pragma unroll
    for (int n = 0; n < N_MODES; ++n) { rr[n] = qr[n]; ri[n] = qi[n]; }
#pragma unroll
    for (int k = 0; k < 6; ++k) {
#pragma unroll
        for (int n = 0; n < N_MODES; ++n) {
            const float a = rr[n], b = ri[n];
            rr[n] = fmaf(a, a, -b * b);
            ri[n] = 2.0f * a * b;
        }
    }

    // ---- inclusive Hillis-Steele scan across 64 lanes: h_l += A^off * h_{l-off} ----
#pragma unroll
    for (int off = 1; off < 64; off <<= 1) {
#pragma unroll
        for (int n = 0; n < N_MODES; ++n) {
            const float pr = __shfl_up(hr[n], off);
            const float pi = __shfl_up(hi[n], off);
            if (lane >= off) {
                const float t0 = fmaf(rr[n], pr, fmaf(-ri[n], pi, hr[n]));
                const float t1 = fmaf(rr[n], pi, fmaf( ri[n], pr, hi[n]));
                hr[n] = t0; hi[n] = t1;
            }
        }
        if (off < 32) {
#pragma unroll
            for (int n = 0; n < N_MODES; ++n) {
                const float a = rr[n], b = ri[n];
                rr[n] = fmaf(a, a, -b * b);
                ri[n] = 2.0f * a * b;
            }
        }
    }

    // ---- exclusive: carry-in = inclusive value of lane-1 (0 for lane 0) ----
#pragma unroll
    for (int n = 0; n < N_MODES; ++n) {
        const float pr = __shfl_up(hr[n], 1);
        const float pi = __shfl_up(hi[n], 1);
        hr[n] = (lane == 0) ? 0.0f : pr;
        hi[n] = (lane == 0) ? 0.0f : pi;
    }

    // ---- projection coefficients (loaded late to shorten live range) ----
    float cr[N_MODES], ci[N_MODES];
#pragma unroll
    for (int n = 0; n < N_MODES; ++n) {
        const int idx = d * N_MODES + n;
        const float p = 1.0f / (1.0f + __expf(-p_logit[idx]));
        const float g = SCALE_F * p;
        cr[n] = gr[idx] * g;
        ci[n] = gi[idx] * g;
    }
    const float om = omega[d];

    // ---- phase 2: recurrence from carry + projection + residual ----
#pragma unroll 2
    for (int j0 = 0; j0 < CHUNK; j0 += 4) {
        const float4 xv = *reinterpret_cast<const float4*>(xrow + j0);
        const float xs[4] = {xv.x, xv.y, xv.z, xv.w};
        float ys[4];
#pragma unroll
        for (int jj = 0; jj < 4; ++jj) {
            const float xe = xs[jj];
            float acc = om * xe;
#pragma unroll
            for (int n = 0; n < N_MODES; ++n) {
                const float t  = fmaf(qr[n], hr[n], xe);
                const float nr = fmaf(-qi[n], hi[n], t);
                const float ni = fmaf(qr[n], hi[n], qi[n] * hr[n]);
                hr[n] = nr; hi[n] = ni;
                acc = fmaf(cr[n], nr, acc);
                acc = fmaf(-ci[n], ni, acc);
            }
            ys[jj] = acc;
        }
        float4 yv; yv.x = ys[0]; yv.y = ys[1]; yv.z = ys[2]; yv.w = ys[3];
        *reinterpret_cast<float4*>(yrow + j0) = yv;
    }
}

extern "C" void kernel_launch(void* const* d_in, const int* in_sizes, int n_in,
                              void* d_out, int out_size, void* d_ws, size_t ws_size,
                              hipStream_t stream)
{
    const float* x   = (const float*)d_in[0];
    const float* pl  = (const float*)d_in[1];
    const float* lqr = (const float*)d_in[2];
    const float* lqi = (const float*)d_in[3];
    const float* gr  = (const float*)d_in[4];
    const float* gi  = (const float*)d_in[5];
    const float* om  = (const float*)d_in[6];
    float* out = (float*)d_out;

    dim3 grid(B_DIM * D_DIM);   // one 64-lane wave per (b, d) row
    dim3 block(64);
    ema_scan_kernel<<<grid, block, 0, stream>>>(x, pl, lqr, lqi, gr, gi, om, out);
}